// Round 7
// baseline (1000.028 us; speedup 1.0000x reference)
//
#include <hip/hip_runtime.h>
#include <hip/hip_bf16.h>

// BailingMoeBlock: T=2048 H=1024 NH=8 NKV=2 HD=128 E=16 TOPK=4 NG=4 TKG=2 F=FS=1024
// Round 11: flash QK^T moved to bf16x3 MFMA (hi/lo split Q,K from k_qkv_post):
//  - A/B fragments read straight from global (layouts identical to the proven
//    gemm_mfma: A[row=fr][k=(lane>>4)*8], C col=fr / row=(lane>>4)*4+reg).
//  - per-wave 32-wide k-slice; softmax via Ms/Mn/Ls LDS exchange (3 barriers);
//    P goes through the UNCHANGED swizzled Ps exchange; PV VALU loop, flush,
//    V path byte-identical to round 10.
//  - no K staging/LDS -> 17KB LDS, launch_bounds(256,3), 768 blocks (3/CU),
//    chains 5-6 units (17b/3), <=4 partials/row, 4-part merge; Op3 in dead
//    act region.
// Everything outside flash/k_qkv_post/k_fmerge identical to round 10.

#define T_TOK 2048
#define H_DIM 1024
#define NHEAD 8
#define NKVH 2
#define HDIM 128
#define QKV_DIM 1536
#define E_EXP 16
#define TOPKE 4
#define F_DIM 1024
#define FS_DIM 1024
#define NPAIR (T_TOK*TOPKE)
#define EPS_F 1e-6f

#define DEV __device__ __forceinline__

typedef __attribute__((ext_vector_type(4))) float f32x4;
typedef __attribute__((ext_vector_type(8))) short s16x8;

DEV float us2f(unsigned short u){ return __uint_as_float(((unsigned int)u)<<16); }
DEV unsigned short f2us(float f){
  __hip_bfloat16 b = __float2bfloat16(f);
  unsigned short u; __builtin_memcpy(&u,&b,2); return u;
}

DEV void gl2lds16(const void* g, void* l){
  __builtin_amdgcn_global_load_lds(
      (const __attribute__((address_space(1))) void*)g,
      (__attribute__((address_space(3))) void*)l, 16, 0, 0);
}

// cumulative units before q-tile qt (per head): C(qt) = (a+1)*(2a+b), a=qt>>2,b=qt&3
DEV int crow(int qt){ int a=qt>>2, b=qt&3; return (a+1)*(2*a+b); }

// ---- block reductions (256 threads = 4 waves) ----
DEV float bred_sum(float v, float* sm){
  #pragma unroll
  for(int o=32;o>0;o>>=1) v += __shfl_down(v,o);
  int w = threadIdx.x>>6, l = threadIdx.x&63;
  __syncthreads();
  if(l==0) sm[w]=v;
  __syncthreads();
  return sm[0]+sm[1]+sm[2]+sm[3];
}

// ---- weight cvt+transpose: out[z][n][k] = bf16(in[z][k][n]) ----
__global__ __launch_bounds__(256) void k_cvt_t(const float* __restrict__ in,
    unsigned short* __restrict__ out, int Kd, int Nd){
  const int z = blockIdx.z;
  const int kb = blockIdx.y*32, nb = blockIdx.x*32;
  __shared__ float Lt[32][33];
  const int tid = threadIdx.x;
  const int r = tid>>3, c4 = (tid&7)*4;
  const float* src = in + (long long)z*Kd*Nd + (long long)(kb+r)*Nd + nb + c4;
  float4 v = *(const float4*)src;
  Lt[r][c4+0]=v.x; Lt[r][c4+1]=v.y; Lt[r][c4+2]=v.z; Lt[r][c4+3]=v.w;
  __syncthreads();
  ushort4 o;
  o.x = f2us(Lt[c4+0][r]); o.y = f2us(Lt[c4+1][r]);
  o.z = f2us(Lt[c4+2][r]); o.w = f2us(Lt[c4+3][r]);
  *(ushort4*)(out + (long long)z*Nd*Kd + (long long)(nb+r)*Kd + kb + c4) = o;
}

// ---- weight cvt+transpose+SPLIT: oh/ol[n][k] = hi/lo bf16 of in[k][n] ----
__global__ __launch_bounds__(256) void k_cvt_t3(const float* __restrict__ in,
    unsigned short* __restrict__ oh, unsigned short* __restrict__ ol,
    int Kd, int Nd){
  const int kb = blockIdx.y*32, nb = blockIdx.x*32;
  __shared__ float Lt[32][33];
  const int tid = threadIdx.x;
  const int r = tid>>3, c4 = (tid&7)*4;
  const float* src = in + (long long)(kb+r)*Nd + nb + c4;
  float4 v = *(const float4*)src;
  Lt[r][c4+0]=v.x; Lt[r][c4+1]=v.y; Lt[r][c4+2]=v.z; Lt[r][c4+3]=v.w;
  __syncthreads();
  ushort4 h4, l4;
  float f;
  f = Lt[c4+0][r]; h4.x = f2us(f); l4.x = f2us(f - us2f(h4.x));
  f = Lt[c4+1][r]; h4.y = f2us(f); l4.y = f2us(f - us2f(h4.y));
  f = Lt[c4+2][r]; h4.z = f2us(f); l4.z = f2us(f - us2f(h4.z));
  f = Lt[c4+3][r]; h4.w = f2us(f); l4.w = f2us(f - us2f(h4.w));
  const long long ob = (long long)(nb+r)*Kd + kb + c4;
  *(ushort4*)(oh + ob) = h4;
  *(ushort4*)(ol + ob) = l4;
}

// ---- MFMA GEMM: C[M x N](bf16) = A[M x K](bf16, opt gather) * Bt[N x K]^T ----
template<bool GROUPED, bool GATHER>
__global__ __launch_bounds__(256) void gemm_mfma(
    const unsigned short* __restrict__ A, int lda,
    const unsigned short* __restrict__ Bt, int ldbt, long long bstride,
    unsigned short* __restrict__ C, int ldc,
    const int* __restrict__ rowidx, const int* __restrict__ grpoff,
    int Mdense, int K){
  const int z = blockIdx.z;
  const int rb = GROUPED ? grpoff[z] : 0;
  const int re = GROUPED ? grpoff[z+1] : Mdense;
  const int m0 = rb + blockIdx.y*128;
  if(m0 >= re) return;
  const int n0 = blockIdx.x*128;
  const unsigned short* Bz = Bt + (long long)z*bstride;

  __shared__ unsigned short As[128][32];   // [m][k] 8KB
  __shared__ unsigned short Bs[128][32];   // [n][k] 8KB

  const int tid = threadIdx.x;
  const int s0 = tid, s1 = tid+256;
  int gr0 = m0 + (s0>>2), gr1 = m0 + (s1>>2);
  if(GROUPED){ gr0 = min(gr0, re-1); gr1 = min(gr1, re-1); }
  if(GATHER){ gr0 = rowidx[gr0]; gr1 = rowidx[gr1]; }
  const unsigned short* ag0 = A + (long long)gr0*lda + (s0&3)*8;
  const unsigned short* ag1 = A + (long long)gr1*lda + (s1&3)*8;
  const unsigned short* bg0 = Bz + (long long)(n0 + (s0>>2))*ldbt + (s0&3)*8;
  const unsigned short* bg1 = Bz + (long long)(n0 + (s1>>2))*ldbt + (s1&3)*8;
  char* asb = (char*)&As[0][0];
  char* bsb = (char*)&Bs[0][0];
  const int wb = (tid & 192)*16;

  const int w = tid>>6, lane = tid&63;
  const int wm = (w>>1)*64, wn = (w&1)*64;
  const int fr = lane&15, q8 = (lane>>4)*8;

  f32x4 zero = {0.f,0.f,0.f,0.f};
  f32x4 acc[4][4];
  #pragma unroll
  for(int mi=0;mi<4;mi++)
    #pragma unroll
    for(int ni=0;ni<4;ni++) acc[mi][ni]=zero;

  for(int k0=0;k0<K;k0+=32){
    __syncthreads();
    gl2lds16(ag0 + k0, asb + wb);
    gl2lds16(ag1 + k0, asb + 4096 + wb);
    gl2lds16(bg0 + k0, bsb + wb);
    gl2lds16(bg1 + k0, bsb + 4096 + wb);
    __syncthreads();
    s16x8 af[4], bf[4];
    #pragma unroll
    for(int mi=0;mi<4;mi++) af[mi] = *(const s16x8*)&As[wm+mi*16+fr][q8];
    #pragma unroll
    for(int ni=0;ni<4;ni++) bf[ni] = *(const s16x8*)&Bs[wn+ni*16+fr][q8];
    #pragma unroll
    for(int mi=0;mi<4;mi++)
      #pragma unroll
      for(int ni=0;ni<4;ni++)
        acc[mi][ni] = __builtin_amdgcn_mfma_f32_16x16x32_bf16(af[mi], bf[ni], acc[mi][ni], 0,0,0);
  }
  const int q4 = (lane>>4)*4;
  #pragma unroll
  for(int mi=0;mi<4;mi++)
    #pragma unroll
    for(int ni=0;ni<4;ni++){
      const int col = n0 + wn + ni*16 + fr;
      #pragma unroll
      for(int r=0;r<4;r++){
        const int row = m0 + wm + mi*16 + q4 + r;
        if(row < re) C[(long long)row*ldc + col] = f2us(acc[mi][ni][r]);
      }
    }
}

// ---- bf16x3 split MFMA GEMM: C[M x N](f32) = A(hi+lo) * B^T(hi+lo), drop lo*lo ----
template<int EPI_ADD>
__global__ __launch_bounds__(256) void gemm_mfma3(
    const unsigned short* __restrict__ Ah, const unsigned short* __restrict__ Al, int lda,
    const unsigned short* __restrict__ Bh, const unsigned short* __restrict__ Bl, int ldbt,
    float* __restrict__ C, int ldc, const float* __restrict__ D, int K){
  const int m0 = blockIdx.y*128;
  const int n0 = blockIdx.x*128;

  __shared__ unsigned short Ash[128][32];
  __shared__ unsigned short Asl[128][32];
  __shared__ unsigned short Bsh[128][32];
  __shared__ unsigned short Bsl[128][32];

  const int tid = threadIdx.x;
  const int s0 = tid, s1 = tid+256;
  const long long ar0 = (long long)(m0 + (s0>>2))*lda + (s0&3)*8;
  const long long ar1 = (long long)(m0 + (s1>>2))*lda + (s1&3)*8;
  const long long br0 = (long long)(n0 + (s0>>2))*ldbt + (s0&3)*8;
  const long long br1 = (long long)(n0 + (s1>>2))*ldbt + (s1&3)*8;
  char* ahb = (char*)&Ash[0][0];
  char* alb = (char*)&Asl[0][0];
  char* bhb = (char*)&Bsh[0][0];
  char* blb = (char*)&Bsl[0][0];
  const int wb = (tid & 192)*16;

  const int w = tid>>6, lane = tid&63;
  const int wm = (w>>1)*64, wn = (w&1)*64;
  const int fr = lane&15, q8 = (lane>>4)*8;

  f32x4 zero = {0.f,0.f,0.f,0.f};
  f32x4 acc[4][4];
  #pragma unroll
  for(int mi=0;mi<4;mi++)
    #pragma unroll
    for(int ni=0;ni<4;ni++) acc[mi][ni]=zero;

  for(int k0=0;k0<K;k0+=32){
    __syncthreads();
    gl2lds16(Ah + ar0 + k0, ahb + wb);
    gl2lds16(Ah + ar1 + k0, ahb + 4096 + wb);
    gl2lds16(Al + ar0 + k0, alb + wb);
    gl2lds16(Al + ar1 + k0, alb + 4096 + wb);
    gl2lds16(Bh + br0 + k0, bhb + wb);
    gl2lds16(Bh + br1 + k0, bhb + 4096 + wb);
    gl2lds16(Bl + br0 + k0, blb + wb);
    gl2lds16(Bl + br1 + k0, blb + 4096 + wb);
    __syncthreads();
    s16x8 afh[4], afl[4], bfh[4], bfl[4];
    #pragma unroll
    for(int mi=0;mi<4;mi++){
      afh[mi] = *(const s16x8*)&Ash[wm+mi*16+fr][q8];
      afl[mi] = *(const s16x8*)&Asl[wm+mi*16+fr][q8];
    }
    #pragma unroll
    for(int ni=0;ni<4;ni++){
      bfh[ni] = *(const s16x8*)&Bsh[wn+ni*16+fr][q8];
      bfl[ni] = *(const s16x8*)&Bsl[wn+ni*16+fr][q8];
    }
    #pragma unroll
    for(int mi=0;mi<4;mi++)
      #pragma unroll
      for(int ni=0;ni<4;ni++){
        acc[mi][ni] = __builtin_amdgcn_mfma_f32_16x16x32_bf16(afh[mi], bfh[ni], acc[mi][ni], 0,0,0);
        acc[mi][ni] = __builtin_amdgcn_mfma_f32_16x16x32_bf16(afh[mi], bfl[ni], acc[mi][ni], 0,0,0);
        acc[mi][ni] = __builtin_amdgcn_mfma_f32_16x16x32_bf16(afl[mi], bfh[ni], acc[mi][ni], 0,0,0);
      }
  }
  const int q4 = (lane>>4)*4;
  #pragma unroll
  for(int mi=0;mi<4;mi++)
    #pragma unroll
    for(int ni=0;ni<4;ni++){
      const int col = n0 + wn + ni*16 + fr;
      #pragma unroll
      for(int r=0;r<4;r++){
        const int row = m0 + wm + mi*16 + q4 + r;
        float v = acc[mi][ni][r];
        if(EPI_ADD) v += D[(long long)row*ldc + col];
        C[(long long)row*ldc + col] = v;
      }
    }
}

// ---- silu-mul ----
__global__ __launch_bounds__(256) void k_silu(const unsigned short* __restrict__ gu,
    unsigned short* __restrict__ act){
  const int r = blockIdx.x, c = threadIdx.x*4;
  const ushort4 g4 = *(const ushort4*)(gu + (long long)r*2048 + c);
  const ushort4 u4 = *(const ushort4*)(gu + (long long)r*2048 + 1024 + c);
  float g[4] = {us2f(g4.x),us2f(g4.y),us2f(g4.z),us2f(g4.w)};
  float u[4] = {us2f(u4.x),us2f(u4.y),us2f(u4.z),us2f(u4.w)};
  ushort4 o;
  o.x = f2us((g[0]/(1.f+__expf(-g[0])))*u[0]);
  o.y = f2us((g[1]/(1.f+__expf(-g[1])))*u[1]);
  o.z = f2us((g[2]/(1.f+__expf(-g[2])))*u[2]);
  o.w = f2us((g[3]/(1.f+__expf(-g[3])))*u[3]);
  *(ushort4*)(act + (long long)r*1024 + c) = o;
}

// ---- K1: resid = hs + residual ; a_hi/a_lo = bf16x2 split of rmsnorm(resid) ----
__global__ __launch_bounds__(256) void k_add_rmsnorm(const float* __restrict__ hs,
    const float* __restrict__ rs, const float* __restrict__ w,
    float* __restrict__ resid, unsigned short* __restrict__ ah,
    unsigned short* __restrict__ al){
  int t = blockIdx.x, tid = threadIdx.x;
  __shared__ float sm[4];
  const long base = (long)t*H_DIM;
  float x[4]; float ss = 0.f;
  #pragma unroll
  for(int i=0;i<4;i++){
    int c = tid + i*256;
    float v = hs[base+c] + rs[base+c];
    x[i]=v; resid[base+c]=v; ss += v*v;
  }
  float tot = bred_sum(ss, sm);
  float rms = rsqrtf(tot/(float)H_DIM + EPS_F);
  #pragma unroll
  for(int i=0;i<4;i++){
    int c = tid + i*256;
    float v = x[i]*rms*w[c];
    unsigned short hh = f2us(v);
    ah[base+c] = hh;
    al[base+c] = f2us(v - us2f(hh));
  }
}

// ---- K3: per-(t,slot) q/k rmsnorm + rope -> bf16 hi/lo, v copy fp32. ----
__global__ __launch_bounds__(64) void k_qkv_post(const float* __restrict__ qkv,
    const float* __restrict__ qw, const float* __restrict__ kw,
    const int* __restrict__ pos,
    unsigned short* __restrict__ qbh, unsigned short* __restrict__ qbl,
    unsigned short* __restrict__ kbh, unsigned short* __restrict__ kbl,
    float* __restrict__ vb){
  int slot = blockIdx.x, t = blockIdx.y, lane = threadIdx.x;
  const float* x = qkv + (long long)t*QKV_DIM + slot*HDIM;
  float x0 = x[lane], x1 = x[lane+64];
  if(slot < 10){
    float ss = x0*x0 + x1*x1;
    #pragma unroll
    for(int o=32;o>0;o>>=1) ss += __shfl_xor(ss,o);
    float rms = rsqrtf(ss/(float)HDIM + EPS_F);
    const float* w = (slot<8)? qw : kw;
    float n0 = x0*rms*w[lane];
    float n1 = x1*rms*w[lane+64];
    float p = (float)pos[t];
    float invf = __expf(-((float)lane/64.f)*9.210340371976184f);
    float ang = p*invf;
    float s = sinf(ang), c = cosf(ang);
    float o0 = n0*c - n1*s;
    float o1 = n1*c + n0*s;
    long long base = (slot<8)? ((long long)slot*T_TOK + t)*HDIM
                             : ((long long)(slot-8)*T_TOK + t)*HDIM;
    unsigned short* dh = (slot<8)? qbh : kbh;
    unsigned short* dl = (slot<8)? qbl : kbl;
    unsigned short h0 = f2us(o0);
    dh[base+lane] = h0;        dl[base+lane] = f2us(o0 - us2f(h0));
    unsigned short h1 = f2us(o1);
    dh[base+lane+64] = h1;     dl[base+lane+64] = f2us(o1 - us2f(h1));
  } else {
    float* dst = vb + ((long long)(slot-10)*T_TOK + t)*HDIM;
    dst[lane]=x0; dst[lane+64]=x1;
  }
}

// ---- K4: flash attention, round-11: MFMA QK (bf16x3) + VALU PV ----
// 768 blocks (3/CU via launch_bounds(256,3)). Block b owns units
// [floor(17b/3), floor(17(b+1)/3)) of the flattened (h,qt,kt) space.
// Per unit: wave w computes S for k-slice [k0+w*32,+32) via 16x16x32 MFMA
// (Q/K hi+lo from global, drop lo*lo); softmax stats in PV layout via
// Ms/Mn/Ls LDS exchange (3 barriers); P through the swizzled Ps exchange;
// PV FMA loop / flush / merge algebra unchanged. <=4 partials per q-row.
#define FBQ 32
#define FBK 128
__global__ __launch_bounds__(256,3) void k_flash(
    const unsigned short* __restrict__ qbh, const unsigned short* __restrict__ qbl,
    const unsigned short* __restrict__ kbh, const unsigned short* __restrict__ kbl,
    const float* __restrict__ vb, float* __restrict__ ctx,
    float* __restrict__ Op1, float* __restrict__ Op2, float* __restrict__ Op3,
    float* __restrict__ Ml){
  const int b = blockIdx.x;
  const int u0 = (17*b)/3, u1 = (17*(b+1))/3;
  const int tid = threadIdx.x;
  const int lane = tid & 63;
  const int w = tid >> 6;
  const int tx = tid & 31;        // PV d-group
  const int ty = tid >> 5;        // PV q-group: rows ty*4+qi
  const int fr = lane & 15;
  const int l4 = lane >> 4;       // 0..3

  __shared__ float4 ps4[1024];    // 16KB swizzled P exchange
  __shared__ float Ms[4][32];
  __shared__ float Ls[4][32];
  __shared__ float Mn[32];
  float* Psf = (float*)ps4;

  const float scale = 0.08838834764831845f;

  // locate starting (h, qt, kt)
  int h = u0/544;
  int r0 = u0 - h*544;
  int qt = 0;
  while(qt < 63 && crow(qt+1) <= r0) qt++;
  int kt = r0 - crow(qt);

  int u = u0;
  while(u < u1){
    const int nkt = (qt>>2) + 1;
    const int q0 = qt * FBQ;
    const int kv = h >> 2;
    const unsigned short* qhp = qbh + ((long long)h*T_TOK + q0)*HDIM;
    const unsigned short* qlp = qbl + ((long long)h*T_TOK + q0)*HDIM;
    const unsigned short* khb = kbh + (long long)kv*T_TOK*HDIM;
    const unsigned short* klb = kbl + (long long)kv*T_TOK*HDIM;
    const float* vbase = vb + (long long)kv*T_TOK*HDIM;
    const int segN = min(nkt - kt, u1 - u);
    const int ktEnd = kt + segN;

    float m_[4], l_[4], O[4][4];
    #pragma unroll
    for(int qi=0;qi<4;qi++){
      m_[qi] = -1e30f; l_[qi] = 0.f;
      #pragma unroll
      for(int j=0;j<4;j++) O[qi][j] = 0.f;
    }

    for(; kt<ktEnd; kt++){
      const int k0 = kt * FBK;
      // ---- (0) MFMA QK: S[2 qtile][2 ktile] for this wave's k-slice ----
      f32x4 sa[2][2];
      f32x4 zero = {0.f,0.f,0.f,0.f};
      sa[0][0]=zero; sa[0][1]=zero; sa[1][0]=zero; sa[1][1]=zero;
      const unsigned short* khp = khb + (long long)(k0 + w*32)*HDIM;
      const unsigned short* klp = klb + (long long)(k0 + w*32)*HDIM;
      #pragma unroll
      for(int dw=0; dw<4; dw++){
        const int doff = dw*32 + l4*8;
        s16x8 a0h = *(const s16x8*)(qhp + (long long)fr*HDIM + doff);
        s16x8 a0l = *(const s16x8*)(qlp + (long long)fr*HDIM + doff);
        s16x8 a1h = *(const s16x8*)(qhp + (long long)(16+fr)*HDIM + doff);
        s16x8 a1l = *(const s16x8*)(qlp + (long long)(16+fr)*HDIM + doff);
        s16x8 b0h = *(const s16x8*)(khp + (long long)fr*HDIM + doff);
        s16x8 b0l = *(const s16x8*)(klp + (long long)fr*HDIM + doff);
        s16x8 b1h = *(const s16x8*)(khp + (long long)(16+fr)*HDIM + doff);
        s16x8 b1l = *(const s16x8*)(klp + (long long)(16+fr)*HDIM + doff);
        sa[0][0] = __builtin_amdgcn_mfma_f32_16x16x32_bf16(a0h,b0h,sa[0][0],0,0,0);
        sa[0][0] = __builtin_amdgcn_mfma_f32_16x16x32_bf16(a0h,b0l,sa[0][0],0,0,0);
        sa[0][0] = __builtin_amdgcn_mfma_f32_16x16x32_bf16(a0l,b0h,sa[0][0],0,0,0);
        sa[0][1] = __builtin_amdgcn_mfma_f32_16x16x32_bf16(a0h,b1h,sa[0][1],0,0,0);
        sa[0][1] = __builtin_amdgcn_mfma_f32_16x16x32_bf16(a0h,b1l,sa[0][1],0,0,0);
        sa[0][1] = __builtin_amdgcn_mfma_f32_16x16x32_bf16(a0l,b1h,sa[0][1],0,0,0);
        sa[1][0] = __builtin_amdgcn_mfma_f32_16x16x32_bf16(a1h,b0h,sa[1][0],0,0,0);
        sa[1][0] = __builtin_amdgcn_mfma_f32_16x16x32_bf16(a1h,b0l,sa[1][0],0,0,0);
        sa[1][0] = __builtin_amdgcn_mfma_f32_16x16x32_bf16(a1l,b0h,sa[1][0],0,0,0);
        sa[1][1] = __builtin_amdgcn_mfma_f32_16x16x32_bf16(a1h,b1h,sa[1][1],0,0,0);
        sa[1][1] = __builtin_amdgcn_mfma_f32_16x16x32_bf16(a1h,b1l,sa[1][1],0,0,0);
        sa[1][1] = __builtin_amdgcn_mfma_f32_16x16x32_bf16(a1l,b1h,sa[1][1],0,0,0);
      }

      // ---- (1) scale + causal mask + per-wave rowmax (over 32 k-cols) ----
      const bool last = (kt == nkt-1);
      const int kg0 = k0 + w*32 + fr;
      const int kg1 = kg0 + 16;
      float rm[2][4];
      #pragma unroll
      for(int q2=0;q2<2;q2++){
        #pragma unroll
        for(int r=0;r<4;r++){
          const int qg = q0 + q2*16 + l4*4 + r;
          float v0 = sa[q2][0][r]*scale;
          float v1 = sa[q2][1][r]*scale;
          if(last && kg0 > qg) v0 = -1e30f;
          if(last && kg1 > qg) v1 = -1e30f;
          sa[q2][0][r] = v0; sa[q2][1][r] = v1;
          rm[q2][r] = fmaxf(v0, v1);
        }
      }
      #pragma unroll
      for(int o=1;o<16;o<<=1){
        #pragma unroll
        for(int q2=0;q2<2;q2++)
          #pragma unroll
          for(int r=0;r<4;r++)
            rm[q2][r] = fmaxf(rm[q2][r], __shfl_xor(rm[q2][r], o));
      }
      if(fr==0){
        #pragma unroll
        for(int q2=0;q2<2;q2++)
          #pragma unroll
          for(int r=0;r<4;r++)
            Ms[w][q2*16 + l4*4 + r] = rm[q2][r];
      }
      __syncthreads();                 // B1: prev PV Ps-reads done; Ms visible

      // ---- (3) PV-role: global max, rescale O/l, publish Mn ----
      #pragma unroll
      for(int qi=0;qi<4;qi++){
        const int row = ty*4 + qi;
        float g = fmaxf(fmaxf(Ms[0][row],Ms[1][row]), fmaxf(Ms[2][row],Ms[3][row]));
        float mn = fmaxf(m_[qi], g);
        float a = __expf(m_[qi] - mn);
        m_[qi] = mn;
        l_[qi] *= a;
        #pragma unroll
        for(int j=0;j<4;j++) O[qi][j] *= a;
      }
      if(tx==0){
        #pragma unroll
        for(int qi=0;qi<4;qi++) Mn[ty*4+qi] = m_[qi];
      }
      __syncthreads();                 // B2: Mn visible

      // ---- (5) QK-role: P=exp(S-mn), Ps store (swizzled), rowsum -> Ls ----
      float rsum[2][4];
      #pragma unroll
      for(int q2=0;q2<2;q2++)
        #pragma unroll
        for(int r=0;r<4;r++) rsum[q2][r] = 0.f;
      #pragma unroll
      for(int q2=0;q2<2;q2++){
        float mnv[4];
        #pragma unroll
        for(int r=0;r<4;r++) mnv[r] = Mn[q2*16 + l4*4 + r];
        #pragma unroll
        for(int k2=0;k2<2;k2++){
          const int kl = w*32 + k2*16 + fr;
          const int qc = q2*4 + l4;
          float4 pv;
          float p;
          p = __expf(sa[q2][k2][0] - mnv[0]); pv.x = p; rsum[q2][0] += p;
          p = __expf(sa[q2][k2][1] - mnv[1]); pv.y = p; rsum[q2][1] += p;
          p = __expf(sa[q2][k2][2] - mnv[2]); pv.z = p; rsum[q2][2] += p;
          p = __expf(sa[q2][k2][3] - mnv[3]); pv.w = p; rsum[q2][3] += p;
          *(float4*)&Psf[(size_t)kl*32 + ((qc ^ ((kl>>2)&7))<<2)] = pv;
        }
      }
      #pragma unroll
      for(int o=1;o<16;o<<=1){
        #pragma unroll
        for(int q2=0;q2<2;q2++)
          #pragma unroll
          for(int r=0;r<4;r++)
            rsum[q2][r] += __shfl_xor(rsum[q2][r], o);
      }
      if(fr==0){
        #pragma unroll
        for(int q2=0;q2<2;q2++)
          #pragma unroll
          for(int r=0;r<4;r++)
            Ls[w][q2*16 + l4*4 + r] = rsum[q2][r];
      }
      __syncthreads();                 // B3: Ps + Ls visible

      // ---- (7) PV-role: l += rowsums; O += P*V (V from global) ----
      #pragma unroll
      for(int qi=0;qi<4;qi++){
        const int row = ty*4 + qi;
        l_[qi] += Ls[0][row] + Ls[1][row] + Ls[2][row] + Ls[3][row];
      }
      const float* vcur = vbase + (long long)k0*HDIM + tx*4;
      #pragma unroll 4
      for(int k=0;k<FBK;k++){
        float4 p4 = *(const float4*)&Psf[(size_t)k*32 + ((ty ^ ((k>>2)&7))<<2)];
        float4 vv = *(const float4*)(vcur + (size_t)k*HDIM);
        O[0][0]=fmaf(p4.x,vv.x,O[0][0]); O[0][1]=fmaf(p4.x,vv.y,O[0][1]);
        O[0][2]=fmaf(p4.x,vv.z,O[0][2]); O[0][3]=fmaf(p4.x,vv.w,O[0][3]);
        O[1][0]=fmaf(p4.y,vv.x,O[1][0]); O[1][1]=fmaf(p4.y,vv.y,O[1][1]);
        O[1][2]=fmaf(p4.y,vv.z,O[1][2]); O[1][3]=fmaf(p4.y,vv.w,O[1][3]);
        O[2][0]=fmaf(p4.z,vv.x,O[2][0]); O[2][1]=fmaf(p4.z,vv.y,O[2][1]);
        O[2][2]=fmaf(p4.z,vv.z,O[2][2]); O[2][3]=fmaf(p4.z,vv.w,O[2][3]);
        O[3][0]=fmaf(p4.w,vv.x,O[3][0]); O[3][1]=fmaf(p4.w,vv.y,O[3][1]);
        O[3][2]=fmaf(p4.w,vv.z,O[3][2]); O[3][3]=fmaf(p4.w,vv.w,O[3][3]);
      }
    }

    // ---- flush segment: unnormalized partial to slot j (0..3) ----
    {
      const int R = (h<<6) + qt;
      const int S = h*544 + crow(qt);
      const int bS = (3*S+2)/17;
      const int j = b - bS;
      #pragma unroll
      for(int qi=0;qi<4;qi++){
        const int row = ty*4 + qi;
        float4 o4 = make_float4(O[qi][0],O[qi][1],O[qi][2],O[qi][3]);
        if(j==0){
          *(float4*)(ctx + (long long)(q0+row)*(NHEAD*HDIM) + h*HDIM + tx*4) = o4;
        } else if(j==1){
          *(float4*)(Op1 + (long long)R*4096 + row*128 + tx*4) = o4;
        } else if(j==2){
          *(float4*)(Op2 + (long long)R*4096 + row*128 + tx*4) = o4;
        } else {
          *(float4*)(Op3 + (long long)R*4096 + row*128 + tx*4) = o4;
        }
        if(tx==0){
          Ml[((R*4+j)<<6) + row*2 + 0] = m_[qi];
          Ml[((R*4+j)<<6) + row*2 + 1] = l_[qi];
        }
      }
    }

    u += segN;
    if(ktEnd == nkt){ kt = 0; qt++; if(qt == 64){ qt = 0; h++; } }
    else kt = ktEnd;
  }
}

// ---- K4b: merge/normalize flash partials (<=4) -> ctx_hi/ctx_lo bf16 split ----
__global__ __launch_bounds__(256) void k_fmerge(const float* __restrict__ ctx,
    const float* __restrict__ Op1, const float* __restrict__ Op2,
    const float* __restrict__ Op3, const float* __restrict__ Ml,
    unsigned short* __restrict__ ch, unsigned short* __restrict__ cl){
  const int wv = threadIdx.x>>6, ln = threadIdx.x&63;
  const int gr = blockIdx.x*4 + wv;          // 0..16383
  const int R = gr>>5, q = gr&31;
  const int h = R>>6, qt = R&63;
  const int nkt = (qt>>2)+1;
  const int S = h*544 + crow(qt);
  const int bS = (3*S+2)/17;
  const int bE = (3*(S+nkt-1)+2)/17;
  const int parts = bE - bS + 1;             // 1..4
  const long long cix = (long long)(qt*32+q)*(NHEAD*HDIM) + h*HDIM + ln*2;
  float2 o0 = *(const float2*)(ctx + cix);
  const float* mlb = Ml + ((R*4)<<6) + q*2;
  float m0 = mlb[0],  l0v = mlb[1];
  float2 o1 = make_float2(0.f,0.f), o2 = o1, o3 = o1;
  float m1=-1e30f,l1v=0.f,m2=-1e30f,l2v=0.f,m3=-1e30f,l3v=0.f;
  float mx = m0;
  if(parts>1){ m1=mlb[64];  l1v=mlb[65];
    o1 = *(const float2*)(Op1 + (long long)R*4096 + q*128 + ln*2); mx=fmaxf(mx,m1); }
  if(parts>2){ m2=mlb[128]; l2v=mlb[129];
    o2 = *(const float2*)(Op2 + (long long)R*4096 + q*128 + ln*2); mx=fmaxf(mx,m2); }
  if(parts>3){ m3=mlb[192]; l3v=mlb[193];
    o3 = *(const float2*)(Op3 + (long long)R*4096 + q*128 + ln*2); mx=fmaxf(mx,m3); }
  float a0 = __expf(m0-mx);
  float a1 = (parts>1)? __expf(m1-mx) : 0.f;
  float a2 = (parts>2)? __expf(m2-mx) : 0.f;
  float a3 = (parts>3)? __expf(m3-mx) : 0.f;
  float inv = 1.f/(l0v*a0 + l1v*a1 + l2v*a2 + l3v*a3);
  float ox = (o0.x*a0 + o1.x*a1 + o2.x*a2 + o3.x*a3)*inv;
  float oy = (o0.y*a0 + o1.y*a1 + o2.y*a2 + o3.y*a3)*inv;
  unsigned short hx = f2us(ox), hy = f2us(oy);
  ch[cix]   = hx; cl[cix]   = f2us(ox - us2f(hx));
  ch[cix+1] = hy; cl[cix+1] = f2us(oy - us2f(hy));
}

// ---- K6: read resid2 (=out1), write h2f (fp32, router) + h2b (bf16, GEMM A) ----
__global__ __launch_bounds__(256) void k_rms2(const float* __restrict__ r2,
    const float* __restrict__ w, float* __restrict__ h2f,
    unsigned short* __restrict__ h2b){
  int t = blockIdx.x, tid = threadIdx.x;
  __shared__ float sm[4];
  const long base = (long)t*H_DIM;
  float x[4]; float ss=0.f;
  #pragma unroll
  for(int i=0;i<4;i++){
    int c = tid+i*256;
    float v = r2[base+c];
    x[i]=v; ss += v*v;
  }
  float tot = bred_sum(ss, sm);
  float rms = rsqrtf(tot/(float)H_DIM + EPS_F);
  #pragma unroll
  for(int i=0;i<4;i++){
    int c = tid+i*256;
    float v = x[i]*rms*w[c];
    h2f[base+c] = v;
    h2b[base+c] = f2us(v);
  }
}

// ---- K7: router (fp32 exact) ----
__global__ __launch_bounds__(256) void k_router(const float* __restrict__ h2,
    const float* __restrict__ gw, const float* __restrict__ eb,
    int* __restrict__ topk_idx, float* __restrict__ topk_w, int* __restrict__ counts){
  int t = blockIdx.x, tid = threadIdx.x;
  int e = tid & 15, seg = tid >> 4;
  const float* hrow = h2 + (long long)t*H_DIM;
  float part = 0.f;
  #pragma unroll 4
  for(int i=0;i<64;i++){
    int hh = seg*64 + i;
    part += hrow[hh]*gw[hh*E_EXP + e];
  }
  __shared__ float pm[16][17];
  __shared__ float sS[16], sfc[16];
  pm[seg][e] = part;
  __syncthreads();
  if(tid < 16){
    float l = 0.f;
    #pragma unroll
    for(int s=0;s<16;s++) l += pm[s][tid];
    float sg = 1.f/(1.f+expf(-l));
    sS[tid]=sg; sfc[tid]=sg+eb[tid];
  }
  __syncthreads();
  if(tid==0){
    float gs[4];
    #pragma unroll
    for(int g=0; g<4; g++){
      float m1=-1e30f, m2=-1e30f;
      for(int j=0;j<4;j++){
        float v=sfc[g*4+j];
        if(v>m1){ m2=m1; m1=v; } else if(v>m2){ m2=v; }
      }
      gs[g]=m1+m2;
    }
    int g1=0; for(int g=1;g<4;g++) if(gs[g]>gs[g1]) g1=g;
    int g2=-1; for(int g=0;g<4;g++){ if(g==g1) continue; if(g2<0||gs[g]>gs[g2]) g2=g; }
    bool taken[16];
    #pragma unroll
    for(int i=0;i<16;i++) taken[i]=false;
    int idx[4];
    for(int j=0;j<4;j++){
      int best=-1; float bv=-1e30f;
      for(int i=0;i<16;i++){
        int g=i>>2;
        if(g!=g1 && g!=g2) continue;
        if(taken[i]) continue;
        if(best<0 || sfc[i]>bv){ best=i; bv=sfc[i]; }
      }
      taken[best]=true; idx[j]=best;
    }
    float w[4]; float s=0.f;
    #pragma unroll
    for(int j=0;j<4;j++){ w[j]=sS[idx[j]]; s+=w[j]; }
    s += 1e-20f;
    #pragma unroll
    for(int j=0;j<4;j++){
      topk_idx[t*4+j]=idx[j];
      topk_w[t*4+j]=w[j]/s;
      atomicAdd(&counts[idx[j]],1);
    }
  }
}

__global__ void k_zero(int* __restrict__ counts){ if(threadIdx.x<16) counts[threadIdx.x]=0; }

__global__ void k_scan(const int* __restrict__ counts, int* __restrict__ offs, int* __restrict__ cursor){
  if(threadIdx.x==0){
    int s=0;
    for(int e2=0;e2<16;e2++){ offs[e2]=s; cursor[e2]=s; s+=counts[e2]; }
    offs[16]=s;
  }
}

__global__ __launch_bounds__(256) void k_scatter(const int* __restrict__ topk_idx,
    int* __restrict__ cursor, int* __restrict__ pair_tok, int* __restrict__ tok2pair){
  int i = blockIdx.x*256 + threadIdx.x;
  int e = topk_idx[i];
  int pos = atomicAdd(&cursor[e],1);
  pair_tok[pos] = i>>2;
  tok2pair[i] = pos;
}

// ---- K15: out0 = sum_j 2*w_j*y[pair_j] + shared (bf16 in, fp32 out) ----
__global__ __launch_bounds__(256) void k_combine(const unsigned short* __restrict__ y,
    const unsigned short* __restrict__ sout, const int* __restrict__ tok2pair,
    const float* __restrict__ topk_w, float* __restrict__ out0){
  int t = blockIdx.x, tid = threadIdx.x;
  int p[4]; float w[4];
  #pragma unroll
  for(int j=0;j<4;j++){ p[j]=tok2pair[t*4+j]; w[j]=topk_w[t*4+j]*2.0f; }
  const long base = (long)t*H_DIM;
  #pragma unroll
  for(int i=0;i<4;i++){
    int c = tid + i*256;
    float v = us2f(sout[base+c]);
    #pragma unroll
    for(int j=0;j<4;j++) v += w[j]*us2f(y[(long long)p[j]*H_DIM + c]);
    out0[base+c] = v;
  }
}

extern "C" void kernel_launch(void* const* d_in, const int* in_sizes, int n_in,
                              void* d_out, int out_size, void* d_ws, size_t ws_size,
                              hipStream_t stream) {
  const float* hs   = (const float*)d_in[0];
  const float* rsd  = (const float*)d_in[1];
  const int*   pos  = (const int*)d_in[2];
  const float* ln1  = (const float*)d_in[3];
  const float* qkvw = (const float*)d_in[4];
  const float* qnw  = (const float*)d_in[5];
  const float* knw  = (const float*)d_in[6];
  const float* dw   = (const float*)d_in[7];
  const float* ln2  = (const float*)d_in[8];
  const float* gw   = (const float*)d_in[9];
  const float* eb   = (const float*)d_in[10];
  const float* w13  = (const float*)d_in[11];
  const float* w2   = (const float*)d_in[12];
  const float* wsgu = (const float*)d_in[13];
  const float* wsd  = (const float*)d_in[14];
  float* out0 = (float*)d_out;
  float* out1 = out0 + (size_t)T_TOK*H_DIM;   // resid2

  char* W = (char*)d_ws;
  float* resid = (float*)(W + 0);
  // h region (8MB @ 8388608): a_hi/a_lo during A..B; flash unnorm ctx during D.
  unsigned short* ah = (unsigned short*)(W + 8388608);    // 4MB
  unsigned short* al = (unsigned short*)(W + 12582912);   // 4MB
  float* ctx   = (float*)(W + 8388608);
  float* qkv   = (float*)(W + 16777216);
  float* h2f   = (float*)(W + 37748736);
  float* vb    = (float*)(W + 48234496);
  // q/k bf16 hi/lo (written C, read D):
  unsigned short* qbh = (unsigned short*)(W + 29360128);  // 4MB
  unsigned short* qbl = (unsigned short*)(W + 33554432);  // 4MB
  unsigned short* kbh = (unsigned short*)(W + 46137344);  // 1MB
  unsigned short* kbl = (unsigned short*)(W + 47185920);  // 1MB
  // flash partial scratch (phase D; qkv/h2f/act regions dead then):
  float* Op1   = (float*)(W + 16777216);            // 8MB (qkv region)
  float* Ml    = (float*)(W + 25165824);            // 512KB
  float* Op2   = (float*)(W + 37748736);            // 8MB (h2f region)
  float* Op3   = (float*)(W + 54525952);            // 8MB (act region, dead in D)
  // ctx bf16 split (written by fmerge; qbh/qbl dead post-flash):
  unsigned short* cth = (unsigned short*)(W + 29360128);  // 4MB
  unsigned short* ctl = (unsigned short*)(W + 33554432);  // 4MB
  // qkv_w^T split (used at B; region scribbled at D -> safe order 0,B,D):
  unsigned short* qwt_h = (unsigned short*)(W + 37748736); // 3MB
  unsigned short* qwt_l = (unsigned short*)(W + 40894464); // 3MB
  // dense_w^T split (used at E; h2b region written at F -> safe):
  unsigned short* dwt_h = (unsigned short*)(W + 50331648); // 2MB
  unsigned short* dwt_l = (unsigned short*)(W + 52428800); // 2MB
  unsigned short* gu    = (unsigned short*)(W + 8388608);
  unsigned short* ybuf  = (unsigned short*)(W + 8388608);
  unsigned short* sgu   = (unsigned short*)(W + 16777216);
  unsigned short* sact  = (unsigned short*)(W + 0);
  unsigned short* sout  = (unsigned short*)(W + 46137344);
  unsigned short* h2b   = (unsigned short*)(W + 50331648);
  unsigned short* act   = (unsigned short*)(W + 54525952);
  unsigned short* w13t  = (unsigned short*)(W + 71303168);
  unsigned short* w2t   = (unsigned short*)(W + 138412032);
  unsigned short* wsgut = (unsigned short*)(W + 171966464);
  unsigned short* wsdt  = (unsigned short*)(W + 176160768);
  float* topkw = (float*)(W + 178257920);
  int* topki   = (int*)(W + 178290688);
  int* ptok    = (int*)(W + 178323456);
  int* t2p     = (int*)(W + 178356224);
  int* cnt     = (int*)(W + 178388992);
  int* offs    = (int*)(W + 178389056);
  int* cur     = (int*)(W + 178389184);

  // 0. weight cvt + transpose -> bf16 B^T (FFN) and bf16x2 split B^T (QKV/dense)
  k_cvt_t<<<dim3(64,32,16), 256, 0, stream>>>(w13,  w13t,  1024, 2048);
  k_cvt_t<<<dim3(32,32,16), 256, 0, stream>>>(w2,   w2t,   1024, 1024);
  k_cvt_t<<<dim3(64,32,1),  256, 0, stream>>>(wsgu, wsgut, 1024, 2048);
  k_cvt_t<<<dim3(32,32,1),  256, 0, stream>>>(wsd,  wsdt,  1024, 1024);
  k_cvt_t3<<<dim3(48,32,1), 256, 0, stream>>>(qkvw, qwt_h, qwt_l, 1024, 1536);
  k_cvt_t3<<<dim3(32,32,1), 256, 0, stream>>>(dw,   dwt_h, dwt_l, 1024, 1024);
  // A. resid + rmsnorm -> bf16x2 split A
  k_add_rmsnorm<<<T_TOK, 256, 0, stream>>>(hs, rsd, ln1, resid, ah, al);
  // B. qkv = h @ qkv_w (bf16x3 MFMA, fp32 out)
  gemm_mfma3<0><<<dim3(QKV_DIM/128, T_TOK/128), 256, 0, stream>>>(
      ah, al, 1024, qwt_h, qwt_l, 1024, qkv, QKV_DIM, nullptr, 1024);
  // C. q/k norm + rope -> bf16 hi/lo
  k_qkv_post<<<dim3(12, T_TOK), 64, 0, stream>>>(qkv, qnw, knw, pos,
      qbh, qbl, kbh, kbl, vb);
  // D. flash attention: 768 chains (5-6 units), MFMA QK + VALU PV, 4-part merge
  k_flash<<<768, 256, 0, stream>>>(qbh, qbl, kbh, kbl, vb, ctx, Op1, Op2, Op3, Ml);
  k_fmerge<<<4096, 256, 0, stream>>>(ctx, Op1, Op2, Op3, Ml, cth, ctl);
  // E. resid2 = ctx @ dense_w + resid -> out1 (bf16x3 MFMA, fp32 out)
  gemm_mfma3<1><<<dim3(H_DIM/128, T_TOK/128), 256, 0, stream>>>(
      cth, ctl, 1024, dwt_h, dwt_l, 1024, out1, H_DIM, resid, 1024);
  // F. h2 = rmsnorm(out1)
  k_rms2<<<T_TOK, 256, 0, stream>>>(out1, ln2, h2f, h2b);
  // G. router
  k_zero<<<1, 64, 0, stream>>>(cnt);
  k_router<<<T_TOK, 256, 0, stream>>>(h2f, gw, eb, topki, topkw, cnt);
  k_scan<<<1, 64, 0, stream>>>(cnt, offs, cur);
  k_scatter<<<NPAIR/256, 256, 0, stream>>>(topki, cur, ptok, t2p);
  // H. shared expert (MFMA)
  gemm_mfma<false,false><<<dim3(16,16,1), 256, 0, stream>>>(
      h2b, 1024, wsgut, 1024, 0, sgu, 2048, nullptr, nullptr, T_TOK, 1024);
  k_silu<<<T_TOK, 256, 0, stream>>>(sgu, sact);
  gemm_mfma<false,false><<<dim3(8,16,1), 256, 0, stream>>>(
      sact, 1024, wsdt, 1024, 0, sout, 1024, nullptr, nullptr, T_TOK, 1024);
  // I. MoE expert FFN (MFMA, grouped)
  gemm_mfma<true,true><<<dim3(16,64,16), 256, 0, stream>>>(
      h2b, 1024, w13t, 1024, (long long)2048*1024, gu, 2048, ptok, offs, 0, 1024);
  k_silu<<<NPAIR, 256, 0, stream>>>(gu, act);
  gemm_mfma<true,false><<<dim3(8,64,16), 256, 0, stream>>>(
      act, 1024, w2t, 1024, (long long)1024*1024, ybuf, 1024, nullptr, offs, 0, 1024);
  // K. combine -> out0
  k_combine<<<T_TOK, 256, 0, stream>>>(ybuf, sout, t2p, topkw, out0);
}